// Round 11
// baseline (568.254 us; speedup 1.0000x reference)
//
#include <hip/hip_runtime.h>
#include <hip/hip_fp16.h>
#include <math.h>

#define NN 50000
#define EE 800000
#define GG 1024
#define HIDD 128
#define NHEAD 4
#define EPTOT (EE + NN)
#define NEG_SLOPE 0.2f
#define NB ((NN + 255) / 256)
#define NTILE (NN / 16)  // 3125 wave-tiles, exact
#define LOG2E 1.4426950408889634f
#define HSLAB (NN * 32)   // elements per head slab (f16): 1.6M

#define BSHIFT 9          // 512 nodes per bucket
#define NBUK 98           // ceil(50000/512)
#define PCHUNK 4096       // edges per partition block
#define BCAP 10240        // staged colb entries per bucket

typedef _Float16 f16x8 __attribute__((ext_vector_type(8)));
typedef float f32x4 __attribute__((ext_vector_type(4)));

__global__ void zero_kernel(float* __restrict__ p, int n) {
  int i = blockIdx.x * blockDim.x + threadIdx.x;
  if (i < n) p[i] = 0.f;
}

__global__ void count_kernel(const int* __restrict__ ei, int* __restrict__ deg) {
  int e = blockIdx.x * blockDim.x + threadIdx.x;
  if (e >= EPTOT) return;
  int d = (e < EE) ? ei[EE + e] : (e - EE);
  atomicAdd(&deg[d], 1);
}

__global__ __launch_bounds__(256) void degsum_kernel(const int* __restrict__ deg,
                                                     int* __restrict__ bsum) {
  __shared__ int sh[256];
  int i = blockIdx.x * 256 + threadIdx.x;
  sh[threadIdx.x] = (i < NN) ? deg[i] : 0;
  __syncthreads();
  for (int off = 128; off > 0; off >>= 1) {
    if (threadIdx.x < off) sh[threadIdx.x] += sh[threadIdx.x + off];
    __syncthreads();
  }
  if (threadIdx.x == 0) bsum[blockIdx.x] = sh[0];
}

// scan block sums; also emits bcur[b] = rowptr[b*512] = exclusive prefix at 2b
__global__ __launch_bounds__(256) void scanb_kernel(const int* __restrict__ bsum,
                                                    int* __restrict__ boff,
                                                    int* __restrict__ rowptr,
                                                    int* __restrict__ bcur) {
  __shared__ int sh[256];
  int t = threadIdx.x;
  int v = (t < NB) ? bsum[t] : 0;
  sh[t] = v;
  __syncthreads();
  for (int off = 1; off < 256; off <<= 1) {
    int u = (t >= off) ? sh[t - off] : 0;
    __syncthreads();
    sh[t] += u;
    __syncthreads();
  }
  if (t < NB) boff[t] = sh[t] - v;
  if (!(t & 1) && (t >> 1) < NBUK) bcur[t >> 1] = sh[t] - v;
  if (t == 255) rowptr[NN] = sh[255];
}

__global__ __launch_bounds__(256) void rowptr_kernel(const int* __restrict__ deg,
                                                     const int* __restrict__ boff,
                                                     int* __restrict__ rowptr) {
  __shared__ int sh[256];
  int t = threadIdx.x;
  int i = blockIdx.x * 256 + t;
  int v = (i < NN) ? deg[i] : 0;
  sh[t] = v;
  __syncthreads();
  for (int off = 1; off < 256; off <<= 1) {
    int u = (t >= off) ? sh[t - off] : 0;
    __syncthreads();
    sh[t] += u;
    __syncthreads();
  }
  if (i < NN) rowptr[i] = boff[blockIdx.x] + sh[t] - v;
}

// Pass A: partition edges into dst-buckets; run-coalesced 8B pair writes.
__global__ __launch_bounds__(256) void partA_kernel(const int* __restrict__ ei,
                                                    int* __restrict__ bcur,
                                                    unsigned long long* __restrict__ pairs) {
  __shared__ int hist[NBUK];
  __shared__ int sbase[NBUK];
  int t = threadIdx.x;
  if (t < NBUK) hist[t] = 0;
  __syncthreads();
  int e0 = blockIdx.x * PCHUNK;
  int ss[16], dd[16];
  int cnt = 0;
#pragma unroll
  for (int i = 0; i < 16; ++i) {
    int e = e0 + i * 256 + t;
    if (e < EPTOT) {
      int s, d;
      if (e < EE) { s = ei[e]; d = ei[EE + e]; } else { s = e - EE; d = s; }
      ss[cnt] = s; dd[cnt] = d; ++cnt;
      atomicAdd(&hist[d >> BSHIFT], 1);
    }
  }
  __syncthreads();
  if (t < NBUK) {
    int h = hist[t];
    sbase[t] = h ? atomicAdd(&bcur[t], h) : 0;
    hist[t] = 0;
  }
  __syncthreads();
  for (int i = 0; i < cnt; ++i) {
    int b = dd[i] >> BSHIFT;
    int pos = sbase[b] + atomicAdd(&hist[b], 1);
    pairs[pos] = ((unsigned long long)(unsigned)dd[i] << 32) | (unsigned)ss[i];
  }
}

// Pass B: one block per bucket; LDS cursors + LDS colb staging; coalesced flush.
__global__ __launch_bounds__(512) void partB_kernel(const unsigned long long* __restrict__ pairs,
                                                    const int* __restrict__ rowptr,
                                                    int* __restrict__ colb) {
  __shared__ int cur[512];
  __shared__ int stage[BCAP];
  int b = blockIdx.x;
  int t = threadIdx.x;
  int node0 = b << BSHIFT;
  int node1 = min(node0 + 512, NN);
  int base = rowptr[node0];
  int nE = rowptr[node1] - base;
  cur[t] = (node0 + t < node1) ? (rowptr[node0 + t] - base) : 0;
  __syncthreads();
  for (int j = t; j < nE; j += 512) {
    unsigned long long p = pairs[base + j];
    int d = (int)(p >> 32);
    int s = (int)(p & 0xffffffffu);
    int pl = atomicAdd(&cur[d - node0], 1);
    if (pl < BCAP) stage[pl] = s;
    else colb[base + pl] = s;
  }
  __syncthreads();
  int lim = min(nE, BCAP);
  for (int j = t; j < lim; j += 512) colb[base + j] = stage[j];
}

__device__ inline float bnelu1(float v, float scale, float shift) {
  v = v * scale + shift;
  return (v > 0.f) ? v : expm1f(v);
}

// pack W[layer] (128x128 f32 row-major) into MFMA A-fragment order, f16.
__global__ __launch_bounds__(256) void prepack_kernel(const float* __restrict__ Ws,
                                                      _Float16* __restrict__ Wp) {
  int f = blockIdx.x * 256 + threadIdx.x;
  if (f >= 3 * 2048) return;
  int layer = f >> 11, r = f & 2047;
  int ctile = r >> 8, ks = (r >> 6) & 3, lane = r & 63;
  const float* W = Ws + (size_t)layer * HIDD * HIDD;
  int col = ctile * 16 + (lane & 15);
  int krow = ks * 32 + (lane >> 4) * 8;
  f16x8 v;
#pragma unroll
  for (int j = 0; j < 8; ++j) v[j] = (_Float16)W[(krow + j) * HIDD + col];
  *(f16x8*)(Wp + f * 8) = v;
}

__global__ void bnfinal_kernel(const float* __restrict__ stat,
                               const float* __restrict__ gamma,
                               const float* __restrict__ beta,
                               float* __restrict__ scsh) {
  int c = threadIdx.x;
  const float invN = 1.f / (float)NN;
  float mean = stat[c] * invN;
  float var = stat[128 + c] * invN - mean * mean;
  float scale = gamma[c] * rsqrtf(var + 1e-5f);
  scsh[c] = scale;
  scsh[128 + c] = beta[c] - mean * scale;
}

// MFMA GEMM, operand-swapped: wave computes 16 nodes x 128 channels.
// Layer 0 reads f32 x (no BN); layers 1,2 read head-major f16 B + fused BN+ELU.
// Outputs head-major: Hh[h][node][0..31], esrc/edst[h][node]. Logits pre-scaled log2e.
__global__ __launch_bounds__(256) void gemm_mfma_kernel(
    const float* __restrict__ Xf, const __half* __restrict__ Xh,
    const _Float16* __restrict__ Wp, const float* __restrict__ scsh,
    const float* __restrict__ asrc, const float* __restrict__ adst,
    __half* __restrict__ Hh, float* __restrict__ esrc, float* __restrict__ edst) {
  int wave = threadIdx.x >> 6, lane = threadIdx.x & 63;
  int jt = blockIdx.x * 4 + wave;
  if (jt >= NTILE) return;
  int nl = lane & 15, kg = lane >> 4;
  int node = jt * 16 + nl;
  f32x4 acc[8];
#pragma unroll
  for (int c = 0; c < 8; ++c) acc[c] = (f32x4){0.f, 0.f, 0.f, 0.f};
#pragma unroll
  for (int ks = 0; ks < 4; ++ks) {
    int k0 = ks * 32 + kg * 8;
    f16x8 bfrag;
    if (Xf) {
      const float* xrow = Xf + node * HIDD;
      float4 va = *(const float4*)(xrow + k0);
      float4 vb = *(const float4*)(xrow + k0 + 4);
      bfrag[0] = (_Float16)va.x; bfrag[1] = (_Float16)va.y;
      bfrag[2] = (_Float16)va.z; bfrag[3] = (_Float16)va.w;
      bfrag[4] = (_Float16)vb.x; bfrag[5] = (_Float16)vb.y;
      bfrag[6] = (_Float16)vb.z; bfrag[7] = (_Float16)vb.w;
    } else {
      // head-major input: channels k0..k0+7 live in head ks, chin kg*8..+8
      float4 raw = *(const float4*)(Xh + ks * HSLAB + node * 32 + kg * 8);
      const __half2* hp = (const __half2*)&raw;
      float4 s0 = *(const float4*)(scsh + k0);
      float4 s1 = *(const float4*)(scsh + k0 + 4);
      float4 t0 = *(const float4*)(scsh + HIDD + k0);
      float4 t1 = *(const float4*)(scsh + HIDD + k0 + 4);
      float2 f0 = __half22float2(hp[0]);
      float2 f1 = __half22float2(hp[1]);
      float2 f2 = __half22float2(hp[2]);
      float2 f3 = __half22float2(hp[3]);
      bfrag[0] = (_Float16)bnelu1(f0.x, s0.x, t0.x);
      bfrag[1] = (_Float16)bnelu1(f0.y, s0.y, t0.y);
      bfrag[2] = (_Float16)bnelu1(f1.x, s0.z, t0.z);
      bfrag[3] = (_Float16)bnelu1(f1.y, s0.w, t0.w);
      bfrag[4] = (_Float16)bnelu1(f2.x, s1.x, t1.x);
      bfrag[5] = (_Float16)bnelu1(f2.y, s1.y, t1.y);
      bfrag[6] = (_Float16)bnelu1(f3.x, s1.z, t1.z);
      bfrag[7] = (_Float16)bnelu1(f3.y, s1.w, t1.w);
    }
#pragma unroll
    for (int c = 0; c < 8; ++c) {
      f16x8 afrag = *(const f16x8*)(Wp + (((c * 4 + ks) * 64 + lane) << 3));
      acc[c] = __builtin_amdgcn_mfma_f32_16x16x32_f16(afrag, bfrag, acc[c], 0, 0, 0);
    }
  }
  float es_p[4] = {0.f, 0.f, 0.f, 0.f};
  float ed_p[4] = {0.f, 0.f, 0.f, 0.f};
#pragma unroll
  for (int c = 0; c < 8; ++c) {
    int ch0 = c * 16 + kg * 4;            // logical channel
    int hd = c >> 1;                      // head
    int chin = (c & 1) * 16 + kg * 4;     // channel within head
    __half2 h01 = __floats2half2_rn(acc[c][0], acc[c][1]);
    __half2 h23 = __floats2half2_rn(acc[c][2], acc[c][3]);
    union { __half2 h[2]; float2 f; } u;
    u.h[0] = h01; u.h[1] = h23;
    *(float2*)(Hh + hd * HSLAB + node * 32 + chin) = u.f;
    float4 av = *(const float4*)(asrc + ch0);
    float4 bv = *(const float4*)(adst + ch0);
    es_p[hd] += acc[c][0] * av.x + acc[c][1] * av.y + acc[c][2] * av.z + acc[c][3] * av.w;
    ed_p[hd] += acc[c][0] * bv.x + acc[c][1] * bv.y + acc[c][2] * bv.z + acc[c][3] * bv.w;
  }
#pragma unroll
  for (int hd = 0; hd < 4; ++hd) {
    es_p[hd] += __shfl_xor(es_p[hd], 16);
    es_p[hd] += __shfl_xor(es_p[hd], 32);
    ed_p[hd] += __shfl_xor(ed_p[hd], 16);
    ed_p[hd] += __shfl_xor(ed_p[hd], 32);
  }
  float es_o = (kg == 0) ? es_p[0] : (kg == 1) ? es_p[1] : (kg == 2) ? es_p[2] : es_p[3];
  float ed_o = (kg == 0) ? ed_p[0] : (kg == 1) ? ed_p[1] : (kg == 2) ? ed_p[2] : ed_p[3];
  esrc[kg * NN + node] = es_o * LOG2E;   // head-major
  edst[kg * NN + node] = ed_o * LOG2E;
}

// Per-head aggregation: wave = one dst node, ONE head (slab 3.2MB -> L2-resident).
// Quarter-waves (16 lanes = 32 ch) process 4 edges per wave-instruction:
// exp/leaky chain amortized 4x; Hh gather = 64B contiguous per quarter.
// Grid: NN/4 blocks x 256 threads = 50000 waves exactly (one per node).
__global__ __launch_bounds__(256) void aggh_kernel(const __half* __restrict__ HhH,
                                                   const float* __restrict__ esrcH,
                                                   const float* __restrict__ edstH,
                                                   const int* __restrict__ rowptr,
                                                   const int* __restrict__ colb,
                                                   const float* __restrict__ biasH,
                                                   __half* __restrict__ outH) {
  int lane = threadIdx.x & 63;
  int wid = (blockIdx.x * 256 + threadIdx.x) >> 6;
  int qw = lane >> 4;        // quarter: edge slot offset
  int cl = lane & 15;        // channel pair within head
  float ed = edstH[wid];
  int e0 = rowptr[wid];
  int deg = rowptr[wid + 1] - e0;
  float den = 0.f, ax = 0.f, ay = 0.f;
  for (int base = 0; base < deg; base += 64) {
    int rem = deg - base;
    if (rem > 64) rem = 64;
    int edg = 0;
    if (base + lane < deg) edg = colb[e0 + base + lane];
    int iters = (rem + 3) >> 2;
    for (int i = 0; i < iters; ++i) {
      int slot = i * 4 + qw;
      int s = __shfl(edg, slot);
      float es = esrcH[s];
      __half2 hv = *(const __half2*)(HhH + s * 32 + cl * 2);
      float z = es + ed;
      z = fmaxf(z, z * NEG_SLOPE);
      float w = exp2f(z);
      w = (base + slot < deg) ? w : 0.f;
      float2 f = __half22float2(hv);
      den += w;
      ax = fmaf(w, f.x, ax);
      ay = fmaf(w, f.y, ay);
    }
  }
  den += __shfl_xor(den, 16); den += __shfl_xor(den, 32);
  ax  += __shfl_xor(ax, 16);  ax  += __shfl_xor(ax, 32);
  ay  += __shfl_xor(ay, 16);  ay  += __shfl_xor(ay, 32);
  if (lane < 16) {
    float inv = 1.f / (den + 1e-16f);
    float vx = ax * inv + biasH[2 * cl];
    float vy = ay * inv + biasH[2 * cl + 1];
    ((__half2*)outH)[wid * 16 + cl] = __floats2half2_rn(vx, vy);
  }
}

// BN stats over head-major B: logical channel c -> slab c>>5, chin c&31
__global__ __launch_bounds__(256) void bnstat_kernel(const __half* __restrict__ X,
                                                     float* __restrict__ stat) {
  __shared__ float sh[256];
  int tid = threadIdx.x;
  int c = tid & 127;
  int half = tid >> 7;
  const __half* Xs = X + (c >> 5) * HSLAB + (c & 31);
  float s = 0.f, q = 0.f;
  for (int r = blockIdx.x * 2 + half; r < NN; r += gridDim.x * 2) {
    float v = __half2float(Xs[r * 32]);
    s += v;
    q += v * v;
  }
  sh[tid] = s;
  __syncthreads();
  if (tid < 128) atomicAdd(&stat[c], s + sh[tid + 128]);
  __syncthreads();
  sh[tid] = q;
  __syncthreads();
  if (tid < 128) atomicAdd(&stat[128 + c], q + sh[tid + 128]);
}

__global__ void gbound_kernel(const int* __restrict__ batch, int* __restrict__ gstart) {
  int i = blockIdx.x * blockDim.x + threadIdx.x;
  if (i >= NN) return;
  int cur = batch[i];
  int prev = (i == 0) ? -1 : batch[i - 1];
  for (int g = prev + 1; g <= cur; ++g) gstart[g] = i;
  if (i == NN - 1) {
    for (int g = cur + 1; g <= GG; ++g) gstart[g] = NN;
  }
}

// fused: segmented mean pool (BN+ELU inline, head-major read) + 2-layer MLP head
__global__ __launch_bounds__(128) void poolhead_kernel(const __half* __restrict__ X,
                                                       const int* __restrict__ gstart,
                                                       const float* __restrict__ scsh,
                                                       const float* __restrict__ w1,
                                                       const float* __restrict__ b1,
                                                       const float* __restrict__ w2,
                                                       const float* __restrict__ b2,
                                                       float* __restrict__ out) {
  __shared__ float pl[HIDD];
  int g = blockIdx.x;
  int c = threadIdx.x;
  float scale = scsh[c];
  float shift = scsh[128 + c];
  const __half* Xs = X + (c >> 5) * HSLAB + (c & 31);
  int n0 = gstart[g], n1 = gstart[g + 1];
  float s = 0.f;
  for (int n = n0; n < n1; ++n)
    s += bnelu1(__half2float(Xs[n * 32]), scale, shift);
  float inv = (n1 > n0) ? 1.f / (float)(n1 - n0) : 0.f;
  pl[c] = s * inv;
  __syncthreads();
  if (c < 64) {
    float acc = b1[c];
#pragma unroll 4
    for (int k = 0; k < HIDD; ++k) acc += pl[k] * w1[k * 64 + c];
    acc = fmaxf(acc, 0.f);
    float v = acc * w2[c];
#pragma unroll
    for (int off = 32; off > 0; off >>= 1) v += __shfl_down(v, off);
    if (c == 0) out[g] = v + b2[0];
  }
}

extern "C" void kernel_launch(void* const* d_in, const int* in_sizes, int n_in,
                              void* d_out, int out_size, void* d_ws, size_t ws_size,
                              hipStream_t stream) {
  const float* x    = (const float*)d_in[0];
  const int* ei     = (const int*)d_in[1];
  const int* batch  = (const int*)d_in[2];
  const float* Ws   = (const float*)d_in[3];
  const float* asrc = (const float*)d_in[4];
  const float* adst = (const float*)d_in[5];
  const float* bias = (const float*)d_in[6];
  const float* gam  = (const float*)d_in[7];
  const float* bet  = (const float*)d_in[8];
  const float* w1   = (const float*)d_in[9];
  const float* b1   = (const float*)d_in[10];
  const float* w2   = (const float*)d_in[11];
  const float* b2   = (const float*)d_in[12];
  float* out = (float*)d_out;

  char* wp = (char*)d_ws;
  auto carve = [&](size_t bytes) -> char* {
    char* p = wp;
    wp += (bytes + 255) & ~(size_t)255;
    return p;
  };
  __half* B     = (__half*)carve((size_t)NN * HIDD * 2);
  __half* Hh    = (__half*)carve((size_t)NN * HIDD * 2);
  _Float16* Wp  = (_Float16*)carve((size_t)3 * HIDD * HIDD * 2);
  float* scsh   = (float*)carve((size_t)3 * 256 * 4);
  float* esrc   = (float*)carve((size_t)NN * NHEAD * 4);
  float* edst   = (float*)carve((size_t)NN * NHEAD * 4);
  int* rowptr   = (int*)carve((size_t)(NN + 1) * 4);
  int* colb     = (int*)carve((size_t)EPTOT * 4);
  unsigned long long* pairs = (unsigned long long*)carve((size_t)EPTOT * 8);
  int* bcur     = (int*)carve((size_t)NBUK * 4);
  int* bsum     = (int*)carve((size_t)NB * 4);
  int* boff     = (int*)carve((size_t)NB * 4);
  int* gstart   = (int*)carve((size_t)(GG + 1) * 4);
  char* z0 = wp;
  int* deg      = (int*)carve((size_t)NN * 4);
  float* stats  = (float*)carve(768 * 4);
  int zcount = (int)((wp - z0) / 4);

  zero_kernel<<<(zcount + 255) / 256, 256, 0, stream>>>((float*)z0, zcount);
  prepack_kernel<<<24, 256, 0, stream>>>(Ws, Wp);
  count_kernel<<<(EPTOT + 255) / 256, 256, 0, stream>>>(ei, deg);
  degsum_kernel<<<NB, 256, 0, stream>>>(deg, bsum);
  scanb_kernel<<<1, 256, 0, stream>>>(bsum, boff, rowptr, bcur);
  rowptr_kernel<<<NB, 256, 0, stream>>>(deg, boff, rowptr);
  partA_kernel<<<(EPTOT + PCHUNK - 1) / PCHUNK, 256, 0, stream>>>(ei, bcur, pairs);
  partB_kernel<<<NBUK, 512, 0, stream>>>(pairs, rowptr, colb);
  gbound_kernel<<<(NN + 255) / 256, 256, 0, stream>>>(batch, gstart);

  for (int l = 0; l < 3; ++l) {
    const float* sc_prev = (l == 0) ? nullptr : scsh + (l - 1) * 256;
    const float* xf = (l == 0) ? x : nullptr;
    const __half* xh = (l == 0) ? nullptr : B;
    gemm_mfma_kernel<<<(NTILE + 3) / 4, 256, 0, stream>>>(
        xf, xh, Wp + (size_t)l * HIDD * HIDD, sc_prev,
        asrc + l * NHEAD * 32, adst + l * NHEAD * 32, Hh, esrc, edst);
    for (int h = 0; h < NHEAD; ++h) {
      aggh_kernel<<<NN / 4, 256, 0, stream>>>(
          Hh + h * HSLAB, esrc + h * NN, edst + h * NN, rowptr, colb,
          bias + l * HIDD + h * 32, B + h * HSLAB);
    }
    bnstat_kernel<<<1024, 256, 0, stream>>>(B, stats + l * 256);
    bnfinal_kernel<<<1, 128, 0, stream>>>(stats + l * 256, gam + l * HIDD,
                                          bet + l * HIDD, scsh + l * 256);
  }
  poolhead_kernel<<<GG, 128, 0, stream>>>(B, gstart, scsh + 2 * 256, w1, b1, w2, b2, out);
}

// Round 12
// 512.783 us; speedup vs baseline: 1.1082x; 1.1082x over previous
//
#include <hip/hip_runtime.h>
#include <hip/hip_fp16.h>
#include <math.h>

#define NN 50000
#define EE 800000
#define GG 1024
#define HIDD 128
#define NHEAD 4
#define EPTOT (EE + NN)
#define NEG_SLOPE 0.2f
#define NB ((NN + 255) / 256)
#define NTILE (NN / 16)  // 3125 wave-tiles, exact
#define LOG2E 1.4426950408889634f
#define HSLAB (NN * 32)   // elements per head slab (f16): 1.6M

#define BSHIFT 9          // 512 nodes per bucket
#define NBUK 98           // ceil(50000/512)
#define PCHUNK 4096       // edges per partition block
#define BCAP 10240        // staged colb entries per bucket

typedef _Float16 f16x8 __attribute__((ext_vector_type(8)));
typedef float f32x4 __attribute__((ext_vector_type(4)));

__global__ void zero_kernel(float* __restrict__ p, int n) {
  int i = blockIdx.x * blockDim.x + threadIdx.x;
  if (i < n) p[i] = 0.f;
}

__global__ void count_kernel(const int* __restrict__ ei, int* __restrict__ deg) {
  int e = blockIdx.x * blockDim.x + threadIdx.x;
  if (e >= EPTOT) return;
  int d = (e < EE) ? ei[EE + e] : (e - EE);
  atomicAdd(&deg[d], 1);
}

__global__ __launch_bounds__(256) void degsum_kernel(const int* __restrict__ deg,
                                                     int* __restrict__ bsum) {
  __shared__ int sh[256];
  int i = blockIdx.x * 256 + threadIdx.x;
  sh[threadIdx.x] = (i < NN) ? deg[i] : 0;
  __syncthreads();
  for (int off = 128; off > 0; off >>= 1) {
    if (threadIdx.x < off) sh[threadIdx.x] += sh[threadIdx.x + off];
    __syncthreads();
  }
  if (threadIdx.x == 0) bsum[blockIdx.x] = sh[0];
}

// scan block sums; also emits bcur[b] = rowptr[b*512] = exclusive prefix at 2b
__global__ __launch_bounds__(256) void scanb_kernel(const int* __restrict__ bsum,
                                                    int* __restrict__ boff,
                                                    int* __restrict__ rowptr,
                                                    int* __restrict__ bcur) {
  __shared__ int sh[256];
  int t = threadIdx.x;
  int v = (t < NB) ? bsum[t] : 0;
  sh[t] = v;
  __syncthreads();
  for (int off = 1; off < 256; off <<= 1) {
    int u = (t >= off) ? sh[t - off] : 0;
    __syncthreads();
    sh[t] += u;
    __syncthreads();
  }
  if (t < NB) boff[t] = sh[t] - v;
  if (!(t & 1) && (t >> 1) < NBUK) bcur[t >> 1] = sh[t] - v;
  if (t == 255) rowptr[NN] = sh[255];
}

__global__ __launch_bounds__(256) void rowptr_kernel(const int* __restrict__ deg,
                                                     const int* __restrict__ boff,
                                                     int* __restrict__ rowptr) {
  __shared__ int sh[256];
  int t = threadIdx.x;
  int i = blockIdx.x * 256 + t;
  int v = (i < NN) ? deg[i] : 0;
  sh[t] = v;
  __syncthreads();
  for (int off = 1; off < 256; off <<= 1) {
    int u = (t >= off) ? sh[t - off] : 0;
    __syncthreads();
    sh[t] += u;
    __syncthreads();
  }
  if (i < NN) rowptr[i] = boff[blockIdx.x] + sh[t] - v;
}

// Pass A: partition edges into dst-buckets; run-coalesced 8B pair writes.
__global__ __launch_bounds__(256) void partA_kernel(const int* __restrict__ ei,
                                                    int* __restrict__ bcur,
                                                    unsigned long long* __restrict__ pairs) {
  __shared__ int hist[NBUK];
  __shared__ int sbase[NBUK];
  int t = threadIdx.x;
  if (t < NBUK) hist[t] = 0;
  __syncthreads();
  int e0 = blockIdx.x * PCHUNK;
  int ss[16], dd[16];
  int cnt = 0;
#pragma unroll
  for (int i = 0; i < 16; ++i) {
    int e = e0 + i * 256 + t;
    if (e < EPTOT) {
      int s, d;
      if (e < EE) { s = ei[e]; d = ei[EE + e]; } else { s = e - EE; d = s; }
      ss[cnt] = s; dd[cnt] = d; ++cnt;
      atomicAdd(&hist[d >> BSHIFT], 1);
    }
  }
  __syncthreads();
  if (t < NBUK) {
    int h = hist[t];
    sbase[t] = h ? atomicAdd(&bcur[t], h) : 0;
    hist[t] = 0;
  }
  __syncthreads();
  for (int i = 0; i < cnt; ++i) {
    int b = dd[i] >> BSHIFT;
    int pos = sbase[b] + atomicAdd(&hist[b], 1);
    pairs[pos] = ((unsigned long long)(unsigned)dd[i] << 32) | (unsigned)ss[i];
  }
}

// Pass B: one block per bucket; LDS cursors + LDS colb staging; coalesced flush.
__global__ __launch_bounds__(512) void partB_kernel(const unsigned long long* __restrict__ pairs,
                                                    const int* __restrict__ rowptr,
                                                    int* __restrict__ colb) {
  __shared__ int cur[512];
  __shared__ int stage[BCAP];
  int b = blockIdx.x;
  int t = threadIdx.x;
  int node0 = b << BSHIFT;
  int node1 = min(node0 + 512, NN);
  int base = rowptr[node0];
  int nE = rowptr[node1] - base;
  cur[t] = (node0 + t < node1) ? (rowptr[node0 + t] - base) : 0;
  __syncthreads();
  for (int j = t; j < nE; j += 512) {
    unsigned long long p = pairs[base + j];
    int d = (int)(p >> 32);
    int s = (int)(p & 0xffffffffu);
    int pl = atomicAdd(&cur[d - node0], 1);
    if (pl < BCAP) stage[pl] = s;
    else colb[base + pl] = s;
  }
  __syncthreads();
  int lim = min(nE, BCAP);
  for (int j = t; j < lim; j += 512) colb[base + j] = stage[j];
}

__device__ inline float bnelu1(float v, float scale, float shift) {
  v = v * scale + shift;
  return (v > 0.f) ? v : expm1f(v);
}

// pack W[layer] (128x128 f32 row-major) into MFMA A-fragment order, f16.
__global__ __launch_bounds__(256) void prepack_kernel(const float* __restrict__ Ws,
                                                      _Float16* __restrict__ Wp) {
  int f = blockIdx.x * 256 + threadIdx.x;
  if (f >= 3 * 2048) return;
  int layer = f >> 11, r = f & 2047;
  int ctile = r >> 8, ks = (r >> 6) & 3, lane = r & 63;
  const float* W = Ws + (size_t)layer * HIDD * HIDD;
  int col = ctile * 16 + (lane & 15);
  int krow = ks * 32 + (lane >> 4) * 8;
  f16x8 v;
#pragma unroll
  for (int j = 0; j < 8; ++j) v[j] = (_Float16)W[(krow + j) * HIDD + col];
  *(f16x8*)(Wp + f * 8) = v;
}

__global__ void bnfinal_kernel(const float* __restrict__ stat,
                               const float* __restrict__ gamma,
                               const float* __restrict__ beta,
                               float* __restrict__ scsh) {
  int c = threadIdx.x;
  const float invN = 1.f / (float)NN;
  float mean = stat[c] * invN;
  float var = stat[128 + c] * invN - mean * mean;
  float scale = gamma[c] * rsqrtf(var + 1e-5f);
  scsh[c] = scale;
  scsh[128 + c] = beta[c] - mean * scale;
}

// MFMA GEMM, operand-swapped: wave computes 16 nodes x 128 channels.
// Layer 0 reads f32 x (no BN); layers 1,2 read head-major f16 B + fused BN+ELU.
// Outputs head-major: Hh[h][node][0..31], esrc/edst[h][node]. Logits pre-scaled log2e.
__global__ __launch_bounds__(256) void gemm_mfma_kernel(
    const float* __restrict__ Xf, const __half* __restrict__ Xh,
    const _Float16* __restrict__ Wp, const float* __restrict__ scsh,
    const float* __restrict__ asrc, const float* __restrict__ adst,
    __half* __restrict__ Hh, float* __restrict__ esrc, float* __restrict__ edst) {
  int wave = threadIdx.x >> 6, lane = threadIdx.x & 63;
  int jt = blockIdx.x * 4 + wave;
  if (jt >= NTILE) return;
  int nl = lane & 15, kg = lane >> 4;
  int node = jt * 16 + nl;
  f32x4 acc[8];
#pragma unroll
  for (int c = 0; c < 8; ++c) acc[c] = (f32x4){0.f, 0.f, 0.f, 0.f};
#pragma unroll
  for (int ks = 0; ks < 4; ++ks) {
    int k0 = ks * 32 + kg * 8;
    f16x8 bfrag;
    if (Xf) {
      const float* xrow = Xf + node * HIDD;
      float4 va = *(const float4*)(xrow + k0);
      float4 vb = *(const float4*)(xrow + k0 + 4);
      bfrag[0] = (_Float16)va.x; bfrag[1] = (_Float16)va.y;
      bfrag[2] = (_Float16)va.z; bfrag[3] = (_Float16)va.w;
      bfrag[4] = (_Float16)vb.x; bfrag[5] = (_Float16)vb.y;
      bfrag[6] = (_Float16)vb.z; bfrag[7] = (_Float16)vb.w;
    } else {
      // head-major input: channels k0..k0+7 live in head ks, chin kg*8..+8
      float4 raw = *(const float4*)(Xh + ks * HSLAB + node * 32 + kg * 8);
      const __half2* hp = (const __half2*)&raw;
      float4 s0 = *(const float4*)(scsh + k0);
      float4 s1 = *(const float4*)(scsh + k0 + 4);
      float4 t0 = *(const float4*)(scsh + HIDD + k0);
      float4 t1 = *(const float4*)(scsh + HIDD + k0 + 4);
      float2 f0 = __half22float2(hp[0]);
      float2 f1 = __half22float2(hp[1]);
      float2 f2 = __half22float2(hp[2]);
      float2 f3 = __half22float2(hp[3]);
      bfrag[0] = (_Float16)bnelu1(f0.x, s0.x, t0.x);
      bfrag[1] = (_Float16)bnelu1(f0.y, s0.y, t0.y);
      bfrag[2] = (_Float16)bnelu1(f1.x, s0.z, t0.z);
      bfrag[3] = (_Float16)bnelu1(f1.y, s0.w, t0.w);
      bfrag[4] = (_Float16)bnelu1(f2.x, s1.x, t1.x);
      bfrag[5] = (_Float16)bnelu1(f2.y, s1.y, t1.y);
      bfrag[6] = (_Float16)bnelu1(f3.x, s1.z, t1.z);
      bfrag[7] = (_Float16)bnelu1(f3.y, s1.w, t1.w);
    }
#pragma unroll
    for (int c = 0; c < 8; ++c) {
      f16x8 afrag = *(const f16x8*)(Wp + (((c * 4 + ks) * 64 + lane) << 3));
      acc[c] = __builtin_amdgcn_mfma_f32_16x16x32_f16(afrag, bfrag, acc[c], 0, 0, 0);
    }
  }
  float es_p[4] = {0.f, 0.f, 0.f, 0.f};
  float ed_p[4] = {0.f, 0.f, 0.f, 0.f};
#pragma unroll
  for (int c = 0; c < 8; ++c) {
    int ch0 = c * 16 + kg * 4;            // logical channel
    int hd = c >> 1;                      // head
    int chin = (c & 1) * 16 + kg * 4;     // channel within head
    __half2 h01 = __floats2half2_rn(acc[c][0], acc[c][1]);
    __half2 h23 = __floats2half2_rn(acc[c][2], acc[c][3]);
    union { __half2 h[2]; float2 f; } u;
    u.h[0] = h01; u.h[1] = h23;
    *(float2*)(Hh + hd * HSLAB + node * 32 + chin) = u.f;
    float4 av = *(const float4*)(asrc + ch0);
    float4 bv = *(const float4*)(adst + ch0);
    es_p[hd] += acc[c][0] * av.x + acc[c][1] * av.y + acc[c][2] * av.z + acc[c][3] * av.w;
    ed_p[hd] += acc[c][0] * bv.x + acc[c][1] * bv.y + acc[c][2] * bv.z + acc[c][3] * bv.w;
  }
#pragma unroll
  for (int hd = 0; hd < 4; ++hd) {
    es_p[hd] += __shfl_xor(es_p[hd], 16);
    es_p[hd] += __shfl_xor(es_p[hd], 32);
    ed_p[hd] += __shfl_xor(ed_p[hd], 16);
    ed_p[hd] += __shfl_xor(ed_p[hd], 32);
  }
  float es_o = (kg == 0) ? es_p[0] : (kg == 1) ? es_p[1] : (kg == 2) ? es_p[2] : es_p[3];
  float ed_o = (kg == 0) ? ed_p[0] : (kg == 1) ? ed_p[1] : (kg == 2) ? ed_p[2] : ed_p[3];
  esrc[kg * NN + node] = es_o * LOG2E;   // head-major
  edst[kg * NN + node] = ed_o * LOG2E;
}

// Per-head aggregation: wave = one dst node, ONE head (slab 3.2MB -> L2-resident).
// Quarter-waves (16 lanes = 32 ch) process 4 edges per wave-instruction, and the
// slot loop is 4-deep batched: 4 shuffles + 8 independent gathers in flight
// before any math (MLP=4 per lane). Grid: NN/4 blocks = 50000 waves exactly.
__global__ __launch_bounds__(256) void aggh_kernel(const __half* __restrict__ HhH,
                                                   const float* __restrict__ esrcH,
                                                   const float* __restrict__ edstH,
                                                   const int* __restrict__ rowptr,
                                                   const int* __restrict__ colb,
                                                   const float* __restrict__ biasH,
                                                   __half* __restrict__ outH) {
  int lane = threadIdx.x & 63;
  int wid = (blockIdx.x * 256 + threadIdx.x) >> 6;
  int qw = lane >> 4;        // quarter: edge slot offset
  int cl = lane & 15;        // channel pair within head
  float ed = edstH[wid];
  int e0 = rowptr[wid];
  int deg = rowptr[wid + 1] - e0;
  float den = 0.f, ax = 0.f, ay = 0.f;
  const __half2* hb = (const __half2*)HhH + cl;   // lane-fixed channel offset
  for (int base = 0; base < deg; base += 64) {
    int rem = deg - base;
    if (rem > 64) rem = 64;
    int edg = 0;
    if (base + lane < deg) edg = colb[e0 + base + lane];
    int iters = (rem + 3) >> 2;
#define EDGE_MATH(EV, HV, SLOT)                    \
    {                                              \
      float z = (EV) + ed;                         \
      z = fmaxf(z, z * NEG_SLOPE);                 \
      float w = exp2f(z);                          \
      w = (base + (SLOT) < deg) ? w : 0.f;         \
      float2 f = __half22float2(HV);               \
      den += w;                                    \
      ax = fmaf(w, f.x, ax);                       \
      ay = fmaf(w, f.y, ay);                       \
    }
    int i = 0;
    for (; i + 4 <= iters; i += 4) {
      int sl0 = (i + 0) * 4 + qw;
      int sl1 = (i + 1) * 4 + qw;
      int sl2 = (i + 2) * 4 + qw;
      int sl3 = (i + 3) * 4 + qw;
      int s0 = __shfl(edg, sl0);
      int s1 = __shfl(edg, sl1);
      int s2 = __shfl(edg, sl2);
      int s3 = __shfl(edg, sl3);
      float E0 = esrcH[s0];
      float E1 = esrcH[s1];
      float E2 = esrcH[s2];
      float E3 = esrcH[s3];
      __half2 H0 = hb[s0 * 16];
      __half2 H1 = hb[s1 * 16];
      __half2 H2 = hb[s2 * 16];
      __half2 H3 = hb[s3 * 16];
      EDGE_MATH(E0, H0, sl0)
      EDGE_MATH(E1, H1, sl1)
      EDGE_MATH(E2, H2, sl2)
      EDGE_MATH(E3, H3, sl3)
    }
    for (; i < iters; ++i) {
      int sl = i * 4 + qw;
      int s = __shfl(edg, sl);
      float E = esrcH[s];
      __half2 H = hb[s * 16];
      EDGE_MATH(E, H, sl)
    }
#undef EDGE_MATH
  }
  den += __shfl_xor(den, 16); den += __shfl_xor(den, 32);
  ax  += __shfl_xor(ax, 16);  ax  += __shfl_xor(ax, 32);
  ay  += __shfl_xor(ay, 16);  ay  += __shfl_xor(ay, 32);
  if (lane < 16) {
    float inv = 1.f / (den + 1e-16f);
    float vx = ax * inv + biasH[2 * cl];
    float vy = ay * inv + biasH[2 * cl + 1];
    ((__half2*)outH)[wid * 16 + cl] = __floats2half2_rn(vx, vy);
  }
}

// BN stats over head-major B: logical channel c -> slab c>>5, chin c&31
__global__ __launch_bounds__(256) void bnstat_kernel(const __half* __restrict__ X,
                                                     float* __restrict__ stat) {
  __shared__ float sh[256];
  int tid = threadIdx.x;
  int c = tid & 127;
  int half = tid >> 7;
  const __half* Xs = X + (c >> 5) * HSLAB + (c & 31);
  float s = 0.f, q = 0.f;
  for (int r = blockIdx.x * 2 + half; r < NN; r += gridDim.x * 2) {
    float v = __half2float(Xs[r * 32]);
    s += v;
    q += v * v;
  }
  sh[tid] = s;
  __syncthreads();
  if (tid < 128) atomicAdd(&stat[c], s + sh[tid + 128]);
  __syncthreads();
  sh[tid] = q;
  __syncthreads();
  if (tid < 128) atomicAdd(&stat[128 + c], q + sh[tid + 128]);
}

__global__ void gbound_kernel(const int* __restrict__ batch, int* __restrict__ gstart) {
  int i = blockIdx.x * blockDim.x + threadIdx.x;
  if (i >= NN) return;
  int cur = batch[i];
  int prev = (i == 0) ? -1 : batch[i - 1];
  for (int g = prev + 1; g <= cur; ++g) gstart[g] = i;
  if (i == NN - 1) {
    for (int g = cur + 1; g <= GG; ++g) gstart[g] = NN;
  }
}

// fused: segmented mean pool (BN+ELU inline, head-major read) + 2-layer MLP head
__global__ __launch_bounds__(128) void poolhead_kernel(const __half* __restrict__ X,
                                                       const int* __restrict__ gstart,
                                                       const float* __restrict__ scsh,
                                                       const float* __restrict__ w1,
                                                       const float* __restrict__ b1,
                                                       const float* __restrict__ w2,
                                                       const float* __restrict__ b2,
                                                       float* __restrict__ out) {
  __shared__ float pl[HIDD];
  int g = blockIdx.x;
  int c = threadIdx.x;
  float scale = scsh[c];
  float shift = scsh[128 + c];
  const __half* Xs = X + (c >> 5) * HSLAB + (c & 31);
  int n0 = gstart[g], n1 = gstart[g + 1];
  float s = 0.f;
  for (int n = n0; n < n1; ++n)
    s += bnelu1(__half2float(Xs[n * 32]), scale, shift);
  float inv = (n1 > n0) ? 1.f / (float)(n1 - n0) : 0.f;
  pl[c] = s * inv;
  __syncthreads();
  if (c < 64) {
    float acc = b1[c];
#pragma unroll 4
    for (int k = 0; k < HIDD; ++k) acc += pl[k] * w1[k * 64 + c];
    acc = fmaxf(acc, 0.f);
    float v = acc * w2[c];
#pragma unroll
    for (int off = 32; off > 0; off >>= 1) v += __shfl_down(v, off);
    if (c == 0) out[g] = v + b2[0];
  }
}

extern "C" void kernel_launch(void* const* d_in, const int* in_sizes, int n_in,
                              void* d_out, int out_size, void* d_ws, size_t ws_size,
                              hipStream_t stream) {
  const float* x    = (const float*)d_in[0];
  const int* ei     = (const int*)d_in[1];
  const int* batch  = (const int*)d_in[2];
  const float* Ws   = (const float*)d_in[3];
  const float* asrc = (const float*)d_in[4];
  const float* adst = (const float*)d_in[5];
  const float* bias = (const float*)d_in[6];
  const float* gam  = (const float*)d_in[7];
  const float* bet  = (const float*)d_in[8];
  const float* w1   = (const float*)d_in[9];
  const float* b1   = (const float*)d_in[10];
  const float* w2   = (const float*)d_in[11];
  const float* b2   = (const float*)d_in[12];
  float* out = (float*)d_out;

  char* wp = (char*)d_ws;
  auto carve = [&](size_t bytes) -> char* {
    char* p = wp;
    wp += (bytes + 255) & ~(size_t)255;
    return p;
  };
  __half* B     = (__half*)carve((size_t)NN * HIDD * 2);
  __half* Hh    = (__half*)carve((size_t)NN * HIDD * 2);
  _Float16* Wp  = (_Float16*)carve((size_t)3 * HIDD * HIDD * 2);
  float* scsh   = (float*)carve((size_t)3 * 256 * 4);
  float* esrc   = (float*)carve((size_t)NN * NHEAD * 4);
  float* edst   = (float*)carve((size_t)NN * NHEAD * 4);
  int* rowptr   = (int*)carve((size_t)(NN + 1) * 4);
  int* colb     = (int*)carve((size_t)EPTOT * 4);
  unsigned long long* pairs = (unsigned long long*)carve((size_t)EPTOT * 8);
  int* bcur     = (int*)carve((size_t)NBUK * 4);
  int* bsum     = (int*)carve((size_t)NB * 4);
  int* boff     = (int*)carve((size_t)NB * 4);
  int* gstart   = (int*)carve((size_t)(GG + 1) * 4);
  char* z0 = wp;
  int* deg      = (int*)carve((size_t)NN * 4);
  float* stats  = (float*)carve(768 * 4);
  int zcount = (int)((wp - z0) / 4);

  zero_kernel<<<(zcount + 255) / 256, 256, 0, stream>>>((float*)z0, zcount);
  prepack_kernel<<<24, 256, 0, stream>>>(Ws, Wp);
  count_kernel<<<(EPTOT + 255) / 256, 256, 0, stream>>>(ei, deg);
  degsum_kernel<<<NB, 256, 0, stream>>>(deg, bsum);
  scanb_kernel<<<1, 256, 0, stream>>>(bsum, boff, rowptr, bcur);
  rowptr_kernel<<<NB, 256, 0, stream>>>(deg, boff, rowptr);
  partA_kernel<<<(EPTOT + PCHUNK - 1) / PCHUNK, 256, 0, stream>>>(ei, bcur, pairs);
  partB_kernel<<<NBUK, 512, 0, stream>>>(pairs, rowptr, colb);
  gbound_kernel<<<(NN + 255) / 256, 256, 0, stream>>>(batch, gstart);

  for (int l = 0; l < 3; ++l) {
    const float* sc_prev = (l == 0) ? nullptr : scsh + (l - 1) * 256;
    const float* xf = (l == 0) ? x : nullptr;
    const __half* xh = (l == 0) ? nullptr : B;
    gemm_mfma_kernel<<<(NTILE + 3) / 4, 256, 0, stream>>>(
        xf, xh, Wp + (size_t)l * HIDD * HIDD, sc_prev,
        asrc + l * NHEAD * 32, adst + l * NHEAD * 32, Hh, esrc, edst);
    for (int h = 0; h < NHEAD; ++h) {
      aggh_kernel<<<NN / 4, 256, 0, stream>>>(
          Hh + h * HSLAB, esrc + h * NN, edst + h * NN, rowptr, colb,
          bias + l * HIDD + h * 32, B + h * HSLAB);
    }
    bnstat_kernel<<<1024, 256, 0, stream>>>(B, stats + l * 256);
    bnfinal_kernel<<<1, 128, 0, stream>>>(stats + l * 256, gam + l * HIDD,
                                          bet + l * HIDD, scsh + l * 256);
  }
  poolhead_kernel<<<GG, 128, 0, stream>>>(B, gstart, scsh + 2 * 256, w1, b1, w2, b2, out);
}

// Round 13
// 377.299 us; speedup vs baseline: 1.5061x; 1.3591x over previous
//
#include <hip/hip_runtime.h>
#include <hip/hip_fp16.h>
#include <math.h>

#define NN 50000
#define EE 800000
#define GG 1024
#define HIDD 128
#define NHEAD 4
#define EPTOT (EE + NN)
#define NEG_SLOPE 0.2f
#define NB ((NN + 255) / 256)
#define NTILE (NN / 16)  // 3125 wave-tiles, exact
#define LOG2E 1.4426950408889634f

#define BSHIFT 9          // 512 nodes per bucket
#define NBUK 98           // ceil(50000/512)
#define PCHUNK 4096       // edges per partition block
#define BCAP 10240        // staged colb entries per bucket

typedef _Float16 f16x8 __attribute__((ext_vector_type(8)));
typedef float f32x4 __attribute__((ext_vector_type(4)));

__global__ void zero_kernel(float* __restrict__ p, int n) {
  int i = blockIdx.x * blockDim.x + threadIdx.x;
  if (i < n) p[i] = 0.f;
}

__global__ void count_kernel(const int* __restrict__ ei, int* __restrict__ deg) {
  int e = blockIdx.x * blockDim.x + threadIdx.x;
  if (e >= EPTOT) return;
  int d = (e < EE) ? ei[EE + e] : (e - EE);
  atomicAdd(&deg[d], 1);
}

__global__ __launch_bounds__(256) void degsum_kernel(const int* __restrict__ deg,
                                                     int* __restrict__ bsum) {
  __shared__ int sh[256];
  int i = blockIdx.x * 256 + threadIdx.x;
  sh[threadIdx.x] = (i < NN) ? deg[i] : 0;
  __syncthreads();
  for (int off = 128; off > 0; off >>= 1) {
    if (threadIdx.x < off) sh[threadIdx.x] += sh[threadIdx.x + off];
    __syncthreads();
  }
  if (threadIdx.x == 0) bsum[blockIdx.x] = sh[0];
}

// scan block sums; also emits bcur[b] = rowptr[b*512] = exclusive prefix at 2b
__global__ __launch_bounds__(256) void scanb_kernel(const int* __restrict__ bsum,
                                                    int* __restrict__ boff,
                                                    int* __restrict__ rowptr,
                                                    int* __restrict__ bcur) {
  __shared__ int sh[256];
  int t = threadIdx.x;
  int v = (t < NB) ? bsum[t] : 0;
  sh[t] = v;
  __syncthreads();
  for (int off = 1; off < 256; off <<= 1) {
    int u = (t >= off) ? sh[t - off] : 0;
    __syncthreads();
    sh[t] += u;
    __syncthreads();
  }
  if (t < NB) boff[t] = sh[t] - v;
  if (!(t & 1) && (t >> 1) < NBUK) bcur[t >> 1] = sh[t] - v;
  if (t == 255) rowptr[NN] = sh[255];
}

__global__ __launch_bounds__(256) void rowptr_kernel(const int* __restrict__ deg,
                                                     const int* __restrict__ boff,
                                                     int* __restrict__ rowptr) {
  __shared__ int sh[256];
  int t = threadIdx.x;
  int i = blockIdx.x * 256 + t;
  int v = (i < NN) ? deg[i] : 0;
  sh[t] = v;
  __syncthreads();
  for (int off = 1; off < 256; off <<= 1) {
    int u = (t >= off) ? sh[t - off] : 0;
    __syncthreads();
    sh[t] += u;
    __syncthreads();
  }
  if (i < NN) rowptr[i] = boff[blockIdx.x] + sh[t] - v;
}

// Pass A: partition edges into dst-buckets; run-coalesced 8B pair writes.
__global__ __launch_bounds__(256) void partA_kernel(const int* __restrict__ ei,
                                                    int* __restrict__ bcur,
                                                    unsigned long long* __restrict__ pairs) {
  __shared__ int hist[NBUK];
  __shared__ int sbase[NBUK];
  int t = threadIdx.x;
  if (t < NBUK) hist[t] = 0;
  __syncthreads();
  int e0 = blockIdx.x * PCHUNK;
  int ss[16], dd[16];
  int cnt = 0;
#pragma unroll
  for (int i = 0; i < 16; ++i) {
    int e = e0 + i * 256 + t;
    if (e < EPTOT) {
      int s, d;
      if (e < EE) { s = ei[e]; d = ei[EE + e]; } else { s = e - EE; d = s; }
      ss[cnt] = s; dd[cnt] = d; ++cnt;
      atomicAdd(&hist[d >> BSHIFT], 1);
    }
  }
  __syncthreads();
  if (t < NBUK) {
    int h = hist[t];
    sbase[t] = h ? atomicAdd(&bcur[t], h) : 0;
    hist[t] = 0;
  }
  __syncthreads();
  for (int i = 0; i < cnt; ++i) {
    int b = dd[i] >> BSHIFT;
    int pos = sbase[b] + atomicAdd(&hist[b], 1);
    pairs[pos] = ((unsigned long long)(unsigned)dd[i] << 32) | (unsigned)ss[i];
  }
}

// Pass B: one block per bucket; LDS cursors + LDS colb staging; coalesced flush.
__global__ __launch_bounds__(512) void partB_kernel(const unsigned long long* __restrict__ pairs,
                                                    const int* __restrict__ rowptr,
                                                    int* __restrict__ colb) {
  __shared__ int cur[512];
  __shared__ int stage[BCAP];
  int b = blockIdx.x;
  int t = threadIdx.x;
  int node0 = b << BSHIFT;
  int node1 = min(node0 + 512, NN);
  int base = rowptr[node0];
  int nE = rowptr[node1] - base;
  cur[t] = (node0 + t < node1) ? (rowptr[node0 + t] - base) : 0;
  __syncthreads();
  for (int j = t; j < nE; j += 512) {
    unsigned long long p = pairs[base + j];
    int d = (int)(p >> 32);
    int s = (int)(p & 0xffffffffu);
    int pl = atomicAdd(&cur[d - node0], 1);
    if (pl < BCAP) stage[pl] = s;
    else colb[base + pl] = s;
  }
  __syncthreads();
  int lim = min(nE, BCAP);
  for (int j = t; j < lim; j += 512) colb[base + j] = stage[j];
}

__device__ inline float bnelu1(float v, float scale, float shift) {
  v = v * scale + shift;
  return (v > 0.f) ? v : expm1f(v);
}

// pack W[layer] (128x128 f32 row-major) into MFMA A-fragment order, f16.
__global__ __launch_bounds__(256) void prepack_kernel(const float* __restrict__ Ws,
                                                      _Float16* __restrict__ Wp) {
  int f = blockIdx.x * 256 + threadIdx.x;
  if (f >= 3 * 2048) return;
  int layer = f >> 11, r = f & 2047;
  int ctile = r >> 8, ks = (r >> 6) & 3, lane = r & 63;
  const float* W = Ws + (size_t)layer * HIDD * HIDD;
  int col = ctile * 16 + (lane & 15);
  int krow = ks * 32 + (lane >> 4) * 8;
  f16x8 v;
#pragma unroll
  for (int j = 0; j < 8; ++j) v[j] = (_Float16)W[(krow + j) * HIDD + col];
  *(f16x8*)(Wp + f * 8) = v;
}

__global__ void bnfinal_kernel(const float* __restrict__ stat,
                               const float* __restrict__ gamma,
                               const float* __restrict__ beta,
                               float* __restrict__ scsh) {
  int c = threadIdx.x;
  const float invN = 1.f / (float)NN;
  float mean = stat[c] * invN;
  float var = stat[128 + c] * invN - mean * mean;
  float scale = gamma[c] * rsqrtf(var + 1e-5f);
  scsh[c] = scale;
  scsh[128 + c] = beta[c] - mean * scale;
}

// MFMA GEMM, operand-swapped: wave computes 16 nodes x 128 channels.
// Layer 0 reads f32 x (no BN); layers 1,2 read f16 B with fused BN+ELU.
// Attention logits written pre-scaled by log2e (agg uses exp2).
__global__ __launch_bounds__(256) void gemm_mfma_kernel(
    const float* __restrict__ Xf, const __half* __restrict__ Xh,
    const _Float16* __restrict__ Wp, const float* __restrict__ scsh,
    const float* __restrict__ asrc, const float* __restrict__ adst,
    __half* __restrict__ Hh, float* __restrict__ esrc, float* __restrict__ edst) {
  int wave = threadIdx.x >> 6, lane = threadIdx.x & 63;
  int jt = blockIdx.x * 4 + wave;
  if (jt >= NTILE) return;
  int nl = lane & 15, kg = lane >> 4;
  int node = jt * 16 + nl;
  f32x4 acc[8];
#pragma unroll
  for (int c = 0; c < 8; ++c) acc[c] = (f32x4){0.f, 0.f, 0.f, 0.f};
#pragma unroll
  for (int ks = 0; ks < 4; ++ks) {
    int k0 = ks * 32 + kg * 8;
    f16x8 bfrag;
    if (Xf) {
      const float* xrow = Xf + node * HIDD;
      float4 va = *(const float4*)(xrow + k0);
      float4 vb = *(const float4*)(xrow + k0 + 4);
      bfrag[0] = (_Float16)va.x; bfrag[1] = (_Float16)va.y;
      bfrag[2] = (_Float16)va.z; bfrag[3] = (_Float16)va.w;
      bfrag[4] = (_Float16)vb.x; bfrag[5] = (_Float16)vb.y;
      bfrag[6] = (_Float16)vb.z; bfrag[7] = (_Float16)vb.w;
    } else {
      float4 raw = *(const float4*)(Xh + node * HIDD + k0);  // 8 halves, 16B
      const __half2* hp = (const __half2*)&raw;
      float4 s0 = *(const float4*)(scsh + k0);
      float4 s1 = *(const float4*)(scsh + k0 + 4);
      float4 t0 = *(const float4*)(scsh + HIDD + k0);
      float4 t1 = *(const float4*)(scsh + HIDD + k0 + 4);
      float2 f0 = __half22float2(hp[0]);
      float2 f1 = __half22float2(hp[1]);
      float2 f2 = __half22float2(hp[2]);
      float2 f3 = __half22float2(hp[3]);
      bfrag[0] = (_Float16)bnelu1(f0.x, s0.x, t0.x);
      bfrag[1] = (_Float16)bnelu1(f0.y, s0.y, t0.y);
      bfrag[2] = (_Float16)bnelu1(f1.x, s0.z, t0.z);
      bfrag[3] = (_Float16)bnelu1(f1.y, s0.w, t0.w);
      bfrag[4] = (_Float16)bnelu1(f2.x, s1.x, t1.x);
      bfrag[5] = (_Float16)bnelu1(f2.y, s1.y, t1.y);
      bfrag[6] = (_Float16)bnelu1(f3.x, s1.z, t1.z);
      bfrag[7] = (_Float16)bnelu1(f3.y, s1.w, t1.w);
    }
#pragma unroll
    for (int c = 0; c < 8; ++c) {
      f16x8 afrag = *(const f16x8*)(Wp + (((c * 4 + ks) * 64 + lane) << 3));
      acc[c] = __builtin_amdgcn_mfma_f32_16x16x32_f16(afrag, bfrag, acc[c], 0, 0, 0);
    }
  }
  float es_p[4] = {0.f, 0.f, 0.f, 0.f};
  float ed_p[4] = {0.f, 0.f, 0.f, 0.f};
  __half* hrow = Hh + node * HIDD;
#pragma unroll
  for (int c = 0; c < 8; ++c) {
    int ch0 = c * 16 + kg * 4;
    __half2 h01 = __floats2half2_rn(acc[c][0], acc[c][1]);
    __half2 h23 = __floats2half2_rn(acc[c][2], acc[c][3]);
    union { __half2 h[2]; float2 f; } u;
    u.h[0] = h01; u.h[1] = h23;
    *(float2*)(hrow + ch0) = u.f;
    float4 av = *(const float4*)(asrc + ch0);
    float4 bv = *(const float4*)(adst + ch0);
    int hd = c >> 1;
    es_p[hd] += acc[c][0] * av.x + acc[c][1] * av.y + acc[c][2] * av.z + acc[c][3] * av.w;
    ed_p[hd] += acc[c][0] * bv.x + acc[c][1] * bv.y + acc[c][2] * bv.z + acc[c][3] * bv.w;
  }
#pragma unroll
  for (int hd = 0; hd < 4; ++hd) {
    es_p[hd] += __shfl_xor(es_p[hd], 16);
    es_p[hd] += __shfl_xor(es_p[hd], 32);
    ed_p[hd] += __shfl_xor(ed_p[hd], 16);
    ed_p[hd] += __shfl_xor(ed_p[hd], 32);
  }
  float es_o = (kg == 0) ? es_p[0] : (kg == 1) ? es_p[1] : (kg == 2) ? es_p[2] : es_p[3];
  float ed_o = (kg == 0) ? ed_p[0] : (kg == 1) ? ed_p[1] : (kg == 2) ? ed_p[2] : ed_p[3];
  esrc[node * 4 + kg] = es_o * LOG2E;
  edst[node * 4 + kg] = ed_o * LOG2E;
}

// one wave per dst node, HALF-WAVE EDGE PAIRING: lane = 4 channels (cl=lane&31),
// half-wave h processes edge 2j+h -> each wave-instruction covers 2 edges.
// exp2 chain amortized 2x; Hh gather 8B/lane (256B/half-wave row). 4-pair batch
// keeps 12 independent gathers in flight. Final shfl_xor(32) combines halves.
__global__ __launch_bounds__(256) void agg_kernel(const __half* __restrict__ Hh,
                                                  const float* __restrict__ esrc,
                                                  const float* __restrict__ edst,
                                                  const int* __restrict__ rowptr,
                                                  const int* __restrict__ colb,
                                                  const float* __restrict__ bias,
                                                  __half* __restrict__ outh) {
  int lane = threadIdx.x & 63;
  int wid = (blockIdx.x * 256 + threadIdx.x) >> 6;
  int half = lane >> 5;
  int cl = lane & 31;           // channel group: channels cl*4 .. cl*4+3
  int hd = cl >> 3;             // head
  float ed = edst[wid * 4 + hd];
  int e0 = rowptr[wid];
  int deg = rowptr[wid + 1] - e0;
  float den = 0.f, a0 = 0.f, a1 = 0.f, a2 = 0.f, a3 = 0.f;
  for (int base = 0; base < deg; base += 64) {
    int rem = deg - base;
    if (rem > 64) rem = 64;
    int edg = 0;
    if (base + lane < deg) edg = colb[e0 + base + lane];
    int pairs = (rem + 1) >> 1;
#define PAIR_MATH(EV, RV, SLOT)                    \
    {                                              \
      float z = (EV) + ed;                         \
      z = fmaxf(z, z * NEG_SLOPE);                 \
      float w = exp2f(z);                          \
      w = (base + (SLOT) < deg) ? w : 0.f;         \
      const __half2* hp_ = (const __half2*)&(RV);  \
      float2 fl = __half22float2(hp_[0]);          \
      float2 fh = __half22float2(hp_[1]);          \
      den += w;                                    \
      a0 = fmaf(w, fl.x, a0);                      \
      a1 = fmaf(w, fl.y, a1);                      \
      a2 = fmaf(w, fh.x, a2);                      \
      a3 = fmaf(w, fh.y, a3);                      \
    }
    int jp = 0;
    for (; jp + 4 <= pairs; jp += 4) {
      int sl0 = 2 * (jp + 0) + half;
      int sl1 = 2 * (jp + 1) + half;
      int sl2 = 2 * (jp + 2) + half;
      int sl3 = 2 * (jp + 3) + half;
      int s0 = __shfl(edg, sl0);
      int s1 = __shfl(edg, sl1);
      int s2 = __shfl(edg, sl2);
      int s3 = __shfl(edg, sl3);
      float E0 = esrc[s0 * 4 + hd];
      float E1 = esrc[s1 * 4 + hd];
      float E2 = esrc[s2 * 4 + hd];
      float E3 = esrc[s3 * 4 + hd];
      float2 R0 = *(const float2*)(Hh + s0 * HIDD + cl * 4);
      float2 R1 = *(const float2*)(Hh + s1 * HIDD + cl * 4);
      float2 R2 = *(const float2*)(Hh + s2 * HIDD + cl * 4);
      float2 R3 = *(const float2*)(Hh + s3 * HIDD + cl * 4);
      PAIR_MATH(E0, R0, sl0)
      PAIR_MATH(E1, R1, sl1)
      PAIR_MATH(E2, R2, sl2)
      PAIR_MATH(E3, R3, sl3)
    }
    for (; jp < pairs; ++jp) {
      int sl = 2 * jp + half;
      int s = __shfl(edg, sl);
      float E = esrc[s * 4 + hd];
      float2 R = *(const float2*)(Hh + s * HIDD + cl * 4);
      PAIR_MATH(E, R, sl)
    }
#undef PAIR_MATH
  }
  den += __shfl_xor(den, 32);
  a0 += __shfl_xor(a0, 32);
  a1 += __shfl_xor(a1, 32);
  a2 += __shfl_xor(a2, 32);
  a3 += __shfl_xor(a3, 32);
  if (lane < 32) {
    float inv = 1.f / (den + 1e-16f);
    float4 bv = *(const float4*)(bias + cl * 4);
    __half2 o01 = __floats2half2_rn(a0 * inv + bv.x, a1 * inv + bv.y);
    __half2 o23 = __floats2half2_rn(a2 * inv + bv.z, a3 * inv + bv.w);
    union { __half2 h[2]; float2 f; } u;
    u.h[0] = o01; u.h[1] = o23;
    *(float2*)(outh + (size_t)wid * HIDD + cl * 4) = u.f;
  }
}

__global__ __launch_bounds__(256) void bnstat_kernel(const __half* __restrict__ X,
                                                     float* __restrict__ stat) {
  __shared__ float sh[256];
  int tid = threadIdx.x;
  int c = tid & 127;
  int half = tid >> 7;
  float s = 0.f, q = 0.f;
  for (int r = blockIdx.x * 2 + half; r < NN; r += gridDim.x * 2) {
    float v = __half2float(X[r * HIDD + c]);
    s += v;
    q += v * v;
  }
  sh[tid] = s;
  __syncthreads();
  if (tid < 128) atomicAdd(&stat[c], s + sh[tid + 128]);
  __syncthreads();
  sh[tid] = q;
  __syncthreads();
  if (tid < 128) atomicAdd(&stat[128 + c], q + sh[tid + 128]);
}

__global__ void gbound_kernel(const int* __restrict__ batch, int* __restrict__ gstart) {
  int i = blockIdx.x * blockDim.x + threadIdx.x;
  if (i >= NN) return;
  int cur = batch[i];
  int prev = (i == 0) ? -1 : batch[i - 1];
  for (int g = prev + 1; g <= cur; ++g) gstart[g] = i;
  if (i == NN - 1) {
    for (int g = cur + 1; g <= GG; ++g) gstart[g] = NN;
  }
}

// fused: segmented mean pool (BN+ELU inline) + 2-layer MLP head
__global__ __launch_bounds__(128) void poolhead_kernel(const __half* __restrict__ X,
                                                       const int* __restrict__ gstart,
                                                       const float* __restrict__ scsh,
                                                       const float* __restrict__ w1,
                                                       const float* __restrict__ b1,
                                                       const float* __restrict__ w2,
                                                       const float* __restrict__ b2,
                                                       float* __restrict__ out) {
  __shared__ float pl[HIDD];
  int g = blockIdx.x;
  int c = threadIdx.x;
  float scale = scsh[c];
  float shift = scsh[128 + c];
  int n0 = gstart[g], n1 = gstart[g + 1];
  float s = 0.f;
  for (int n = n0; n < n1; ++n)
    s += bnelu1(__half2float(X[n * HIDD + c]), scale, shift);
  float inv = (n1 > n0) ? 1.f / (float)(n1 - n0) : 0.f;
  pl[c] = s * inv;
  __syncthreads();
  if (c < 64) {
    float acc = b1[c];
#pragma unroll 4
    for (int k = 0; k < HIDD; ++k) acc += pl[k] * w1[k * 64 + c];
    acc = fmaxf(acc, 0.f);
    float v = acc * w2[c];
#pragma unroll
    for (int off = 32; off > 0; off >>= 1) v += __shfl_down(v, off);
    if (c == 0) out[g] = v + b2[0];
  }
}

extern "C" void kernel_launch(void* const* d_in, const int* in_sizes, int n_in,
                              void* d_out, int out_size, void* d_ws, size_t ws_size,
                              hipStream_t stream) {
  const float* x    = (const float*)d_in[0];
  const int* ei     = (const int*)d_in[1];
  const int* batch  = (const int*)d_in[2];
  const float* Ws   = (const float*)d_in[3];
  const float* asrc = (const float*)d_in[4];
  const float* adst = (const float*)d_in[5];
  const float* bias = (const float*)d_in[6];
  const float* gam  = (const float*)d_in[7];
  const float* bet  = (const float*)d_in[8];
  const float* w1   = (const float*)d_in[9];
  const float* b1   = (const float*)d_in[10];
  const float* w2   = (const float*)d_in[11];
  const float* b2   = (const float*)d_in[12];
  float* out = (float*)d_out;

  char* wp = (char*)d_ws;
  auto carve = [&](size_t bytes) -> char* {
    char* p = wp;
    wp += (bytes + 255) & ~(size_t)255;
    return p;
  };
  __half* B     = (__half*)carve((size_t)NN * HIDD * 2);
  __half* Hh    = (__half*)carve((size_t)NN * HIDD * 2);
  _Float16* Wp  = (_Float16*)carve((size_t)3 * HIDD * HIDD * 2);
  float* scsh   = (float*)carve((size_t)3 * 256 * 4);
  float* esrc   = (float*)carve((size_t)NN * NHEAD * 4);
  float* edst   = (float*)carve((size_t)NN * NHEAD * 4);
  int* rowptr   = (int*)carve((size_t)(NN + 1) * 4);
  int* colb     = (int*)carve((size_t)EPTOT * 4);
  unsigned long long* pairs = (unsigned long long*)carve((size_t)EPTOT * 8);
  int* bcur     = (int*)carve((size_t)NBUK * 4);
  int* bsum     = (int*)carve((size_t)NB * 4);
  int* boff     = (int*)carve((size_t)NB * 4);
  int* gstart   = (int*)carve((size_t)(GG + 1) * 4);
  char* z0 = wp;
  int* deg      = (int*)carve((size_t)NN * 4);
  float* stats  = (float*)carve(768 * 4);
  int zcount = (int)((wp - z0) / 4);

  zero_kernel<<<(zcount + 255) / 256, 256, 0, stream>>>((float*)z0, zcount);
  prepack_kernel<<<24, 256, 0, stream>>>(Ws, Wp);
  count_kernel<<<(EPTOT + 255) / 256, 256, 0, stream>>>(ei, deg);
  degsum_kernel<<<NB, 256, 0, stream>>>(deg, bsum);
  scanb_kernel<<<1, 256, 0, stream>>>(bsum, boff, rowptr, bcur);
  rowptr_kernel<<<NB, 256, 0, stream>>>(deg, boff, rowptr);
  partA_kernel<<<(EPTOT + PCHUNK - 1) / PCHUNK, 256, 0, stream>>>(ei, bcur, pairs);
  partB_kernel<<<NBUK, 512, 0, stream>>>(pairs, rowptr, colb);
  gbound_kernel<<<(NN + 255) / 256, 256, 0, stream>>>(batch, gstart);

  for (int l = 0; l < 3; ++l) {
    const float* sc_prev = (l == 0) ? nullptr : scsh + (l - 1) * 256;
    const float* xf = (l == 0) ? x : nullptr;
    const __half* xh = (l == 0) ? nullptr : B;
    gemm_mfma_kernel<<<(NTILE + 3) / 4, 256, 0, stream>>>(
        xf, xh, Wp + (size_t)l * HIDD * HIDD, sc_prev,
        asrc + l * NHEAD * 32, adst + l * NHEAD * 32, Hh, esrc, edst);
    agg_kernel<<<(NN * 64 + 255) / 256, 256, 0, stream>>>(
        Hh, esrc, edst, rowptr, colb, bias + l * HIDD, B);
    bnstat_kernel<<<1024, 256, 0, stream>>>(B, stats + l * 256);
    bnfinal_kernel<<<1, 128, 0, stream>>>(stats + l * 256, gam + l * HIDD,
                                          bet + l * HIDD, scsh + l * 256);
  }
  poolhead_kernel<<<GG, 128, 0, stream>>>(B, gstart, scsh + 2 * 256, w1, b1, w2, b2, out);
}